// Round 1
// baseline (234.598 us; speedup 1.0000x reference)
//
#include <hip/hip_runtime.h>
#include <math.h>

#define IN_H 76
#define IN_W 76
#define HW   (IN_H*IN_W)          // 5776
#define BS   32
#define T    20
#define NC   80
#define ACT  (3*HW)               // 17328 cells per batch
#define CHUNKS 68                 // ceil(17328/256)
#define NPB  (BS*CHUNKS)          // 2176 partial slots for dense kernel
#define EPSC 1e-7f

// raw anchors; scaled by stride 608/76 = 8 at use (all /8 values exact in fp32)
__device__ __constant__ float d_anch[18] = {
    12,16, 19,36, 40,28, 36,75, 76,55, 72,146, 142,110, 192,243, 459,401};

// Module-scope partial buffers — replaces d_ws usage. Poison-safe: every slot
// is unconditionally written each call before yolo_final reads it.
__device__ float2 g_partB[NPB];     // 2176 * 8 B
__device__ float4 g_partC[BS * T];  // 640 * 16 B

__device__ __forceinline__ float fsig(float x) {
    return __builtin_amdgcn_rcpf(1.f + __expf(-x));
}
__device__ __forceinline__ int mask0_of(int l) { return (l == 0) ? 6 : ((l == 1) ? 3 : 0); }

// first-occurrence argmax over 9 anchors of zero-centered wh IoU (matches jnp.argmax)
__device__ __forceinline__ int anchor_match(float gw, float gh) {
    float best = -1.f; int bn = 0;
    #pragma unroll
    for (int n = 0; n < 9; n++) {
        const float aw = d_anch[2*n]   * 0.125f;
        const float ah = d_anch[2*n+1] * 0.125f;
        const float inter = fminf(gw, aw) * fminf(gh, ah);
        const float uni   = gw * gh + aw * ah - inter;
        const float r = inter / uni;
        if (r > best) { best = r; bn = n; }
    }
    return bn;
}

// ---------------- dense: conf-BCE + ignore mask; grid (68, 32), batch-uniform blocks ----
__global__ __launch_bounds__(256) void yolo_dense(
        const float* __restrict__ inp, const int* __restrict__ lp,
        const float* __restrict__ targets) {
    __shared__ float4 s_c[T];   // gminx, gminy, gmaxx, gmaxy
    __shared__ float2 s_m[T];   // ga, auxm (int bits)
    const int b = blockIdx.y;
    const int c = blockIdx.x * 256 + threadIdx.x;
    const int l  = *lp;
    const int m0 = mask0_of(l);

    if (threadIdx.x < T) {
        const float* tp = targets + (size_t)(b * T + threadIdx.x) * 5;
        const float gx = tp[0] * 76.f, gy = tp[1] * 76.f;
        const float gw = tp[2] * 76.f, gh = tp[3] * 76.f;
        const int k = anchor_match(gw, gh) - m0;
        const bool valid = (k >= 0) && (k < 3);
        const int gi = min(max((int)floorf(gx), 0), IN_W - 1);
        const int gj = min(max((int)floorf(gy), 0), IN_H - 1);
        const int auxm = valid ? (1 | (k << 1) | (gj << 3) | (gi << 10)) : -1;
        s_c[threadIdx.x] = make_float4(gx - gw * 0.5f, gy - gh * 0.5f,
                                       gx + gw * 0.5f, gy + gh * 0.5f);
        s_m[threadIdx.x] = make_float2(gw * gh, __int_as_float(auxm));
    }
    __syncthreads();

    float v0 = 0.f, v1 = 0.f;
    if (c < ACT) {
        const int a  = c / HW;
        const int r2 = c - a * HW;
        const int j  = r2 / IN_W;
        const int i  = r2 - j * IN_W;
        const float aw = d_anch[2*(m0+a)]   * 0.125f;
        const float ah = d_anch[2*(m0+a)+1] * 0.125f;

        const float* base = inp + ((size_t)b * 255 + a * 85) * HW + r2;
        const float c0 = base[0];
        const float c1 = base[HW];
        const float c2 = base[2 * HW];
        const float c3 = base[3 * HW];
        const float c4 = base[4 * HW];

        const float px = (float)i + fsig(c0);
        const float py = (float)j + fsig(c1);
        const float pw = __expf(c2) * aw;
        const float ph = __expf(c3) * ah;
        const float conf = fsig(c4);

        const float pminx = px - pw * 0.5f, pmaxx = px + pw * 0.5f;
        const float pminy = py - ph * 0.5f, pmaxy = py + ph * 0.5f;
        const float pa = pw * ph;
        const int want = 1 | (a << 1) | (j << 3) | (i << 10);

        bool ign = false, obj = false;
        #pragma unroll
        for (int t = 0; t < T; t++) {
            const float4 gc = s_c[t];
            const float2 gm = s_m[t];
            const float iw = fmaxf(fminf(gc.z, pmaxx) - fmaxf(gc.x, pminx), 0.f);
            const float ih = fmaxf(fminf(gc.w, pmaxy) - fmaxf(gc.y, pminy), 0.f);
            const float inter = iw * ih;
            // iou > 0.5  <=>  inter/(ga+pa-inter) > 0.5  <=>  3*inter > ga+pa  (division-free)
            ign = ign || (3.f * inter > gm.x + pa);
            obj = obj || (__float_as_int(gm.y) == want);
        }
        const float p = fminf(fmaxf(conf, EPSC), 1.f - EPSC);
        const float bce = obj ? -__logf(p) : -__logf(1.f - p);
        const float mask = (obj || !ign) ? 1.f : 0.f;
        v0 = bce * mask; v1 = mask;
    }

    // wave + block reduce -> ONE unconditional store per block (no atomics, no zero-init)
    #pragma unroll
    for (int off = 32; off; off >>= 1) {
        v0 += __shfl_down(v0, off, 64);
        v1 += __shfl_down(v1, off, 64);
    }
    __shared__ float r0[4], r1[4];
    const int lane = threadIdx.x & 63, wv = threadIdx.x >> 6;
    if (lane == 0) { r0[wv] = v0; r1[wv] = v1; }
    __syncthreads();
    if (threadIdx.x == 0) {
        g_partB[b * CHUNKS + blockIdx.x] =
            make_float2(r0[0] + r0[1] + r0[2] + r0[3],
                        r1[0] + r1[1] + r1[2] + r1[3]);
    }
}

// ---------------- sparse: CIoU + class-BCE, one wave per target; 160 blocks ----------
__global__ __launch_bounds__(256) void yolo_sparse(
        const float* __restrict__ inp, const int* __restrict__ lp,
        const float* __restrict__ targets) {
    const int wid  = blockIdx.x * 4 + (threadIdx.x >> 6);  // target 0..639
    const int lane = threadIdx.x & 63;
    const int b = wid / T, t = wid - b * T;
    const int l  = *lp;
    const int m0 = mask0_of(l);

    // my target (wave-uniform)
    const float* tp = targets + (size_t)(b * T + t) * 5;
    const float gx = tp[0] * 76.f, gy = tp[1] * 76.f;
    const float gw = tp[2] * 76.f, gh = tp[3] * 76.f;
    const int cls = (int)tp[4];
    const int k = anchor_match(gw, gh) - m0;
    const bool valid = (k >= 0) && (k < 3);
    const int gi = min(max((int)floorf(gx), 0), IN_W - 1);
    const int gj = min(max((int)floorf(gy), 0), IN_H - 1);
    const int mycell = valid ? ((k * IN_H + gj) * IN_W + gi) : -1;

    // per-lane cell of target `lane` (for last-write-wins resolution)
    int cell = -3;
    if (lane < T) {
        const float* tq = targets + (size_t)(b * T + lane) * 5;
        const float qx = tq[0] * 76.f, qy = tq[1] * 76.f;
        const float qw = tq[2] * 76.f, qh = tq[3] * 76.f;
        const int qk = anchor_match(qw, qh) - m0;
        if (qk >= 0 && qk < 3) {
            const int qi = min(max((int)floorf(qx), 0), IN_W - 1);
            const int qj = min(max((int)floorf(qy), 0), IN_H - 1);
            cell = (qk * IN_H + qj) * IN_W + qi;
        } else cell = -1;
    }
    const unsigned long long later = __ballot((lane > t) && (cell == mycell));
    const bool win = valid && (later == 0ULL);   // wave-uniform
    if (!win) {
        if (lane == 0) g_partC[wid] = make_float4(0.f, 0.f, 0.f, 0.f);
        return;
    }

    const float* base = inp + ((size_t)b * 255 + k * 85) * HW + gj * IN_W + gi;

    // class BCE: lane covers class lane (+ lane+64 for lane<16)
    float s;
    {
        float pc = fminf(fmaxf(fsig(base[(size_t)(5 + lane) * HW]), EPSC), 1.f - EPSC);
        s = (lane == cls) ? -__logf(pc) : -__logf(1.f - pc);
        if (lane < NC - 64) {
            const int c2 = lane + 64;
            float pc2 = fminf(fmaxf(fsig(base[(size_t)(5 + c2) * HW]), EPSC), 1.f - EPSC);
            s += (c2 == cls) ? -__logf(pc2) : -__logf(1.f - pc2);
        }
    }
    #pragma unroll
    for (int off = 32; off; off >>= 1) s += __shfl_down(s, off, 64);

    if (lane == 0) {
        const float aw = d_anch[2*(m0+k)]   * 0.125f;
        const float ah = d_anch[2*(m0+k)+1] * 0.125f;
        const float px = (float)gi + fsig(base[0]);
        const float py = (float)gj + fsig(base[HW]);
        const float pw = __expf(base[2 * HW]) * aw;
        const float ph = __expf(base[3 * HW]) * ah;

        const float p1x = px - pw * 0.5f, p2x = px + pw * 0.5f;
        const float p1y = py - ph * 0.5f, p2y = py + ph * 0.5f;
        const float g1x = gx - gw * 0.5f, g2x = gx + gw * 0.5f;
        const float g1y = gy - gh * 0.5f, g2y = gy + gh * 0.5f;
        const float iw = fmaxf(fminf(p2x, g2x) - fmaxf(p1x, g1x), 0.f);
        const float ih = fmaxf(fminf(p2y, g2y) - fmaxf(p1y, g1y), 0.f);
        const float inter = iw * ih;
        const float uni = pw * ph + gw * gh - inter;
        const float iou = inter / fmaxf(uni, 1e-6f);
        const float dx = px - gx, dy = py - gy;
        const float cd = dx * dx + dy * dy;
        const float ew = fmaxf(fmaxf(p2x, g2x) - fminf(p1x, g1x), 0.f);
        const float eh = fmaxf(fmaxf(p2y, g2y) - fminf(p1y, g1y), 0.f);
        const float ed = ew * ew + eh * eh;
        float ciou = iou - cd / fmaxf(ed, 1e-6f);
        const float dat = atanf(pw / fmaxf(ph, 1e-6f)) - atanf(gw / fmaxf(gh, 1e-6f));
        const float v = (4.f / (float)(M_PI * M_PI)) * dat * dat;
        const float alpha = v / fmaxf(1.f - iou + v, 1e-6f);
        ciou = ciou - alpha * v;
        g_partC[wid] = make_float4(1.f - ciou, s, 1.f, 0.f);
    }
}

// ---------------- final: reduce 2176 float2 + 640 float4, combine ----------------
__global__ __launch_bounds__(256) void yolo_final(
        const int* __restrict__ lp, float* __restrict__ out) {
    float a0 = 0.f, a1 = 0.f, a2 = 0.f, a3 = 0.f, a4 = 0.f;
    for (int k = threadIdx.x; k < NPB; k += 256) {
        const float2 v = g_partB[k]; a0 += v.x; a1 += v.y;
    }
    for (int k = threadIdx.x; k < BS * T; k += 256) {
        const float4 v = g_partC[k]; a2 += v.x; a3 += v.y; a4 += v.z;
    }
    #pragma unroll
    for (int off = 32; off; off >>= 1) {
        a0 += __shfl_down(a0, off, 64);
        a1 += __shfl_down(a1, off, 64);
        a2 += __shfl_down(a2, off, 64);
        a3 += __shfl_down(a3, off, 64);
        a4 += __shfl_down(a4, off, 64);
    }
    __shared__ float red[4][5];
    const int lane = threadIdx.x & 63, wv = threadIdx.x >> 6;
    if (lane == 0) { red[wv][0]=a0; red[wv][1]=a1; red[wv][2]=a2; red[wv][3]=a3; red[wv][4]=a4; }
    __syncthreads();
    if (threadIdx.x == 0) {
        float s0=0,s1=0,s2=0,s3=0,s4=0;
        #pragma unroll
        for (int w = 0; w < 4; w++) {
            s0+=red[w][0]; s1+=red[w][1]; s2+=red[w][2]; s3+=red[w][3]; s4+=red[w][4];
        }
        const int l = *lp;
        const float balance = (l == 0) ? 0.4f : ((l == 1) ? 1.0f : 4.0f);
        const float obj_ratio = 5.f * (608.f * 608.f) / (416.f * 416.f);
        const float no = fmaxf(s4, 1.f);
        const float loss_loc  = s2 / no * 0.05f;
        const float loss_cls  = s3 / (no * (float)NC);   // cls_ratio = 1
        const float loss_conf = s0 / fmaxf(s1, 1.f) * balance * obj_ratio;
        out[0] = loss_loc + loss_conf + loss_cls;
    }
}

extern "C" void kernel_launch(void* const* d_in, const int* in_sizes, int n_in,
                              void* d_out, int out_size, void* d_ws, size_t ws_size,
                              hipStream_t stream) {
    const float* inp     = (const float*)d_in[0];
    const float* targets = (const float*)d_in[1];
    const int*   lp      = (const int*)d_in[2];
    float* out = (float*)d_out;
    (void)d_ws; (void)ws_size;   // workspace deliberately untouched this round

    dim3 gridB(CHUNKS, BS);
    yolo_dense <<<gridB, 256, 0, stream>>>(inp, lp, targets);
    yolo_sparse<<<(BS * T) / 4, 256, 0, stream>>>(inp, lp, targets);
    yolo_final <<<1, 256, 0, stream>>>(lp, out);
}